// Round 4
// baseline (164.427 us; speedup 1.0000x reference)
//
#include <hip/hip_runtime.h>

#define B_ 8
#define S_ 4096
#define D_ 64
#define NCHUNK 64          // chunks per batch; 64 rows per chunk, 2 stages
#define RPC (S_ / NCHUNK)  // 64 rows per chunk

// ---------------------------------------------------------------------------
// Kernel 1: block = (batch, chunk). Two unrolled 32-row stages; all global
// loads (16 float4/thread) issued before any compute; RoPE in registers;
// 4x4 register-tile outer product from LDS. Writes one 64x64 partial tile.
// ---------------------------------------------------------------------------
__global__ void rope_ktv_partials(
    const float* __restrict__ K, const float* __restrict__ V,
    const float* __restrict__ FK, const float* __restrict__ FV,
    float* __restrict__ part)
{
    __shared__ float kbuf[32][64];
    __shared__ float vbuf[32][64];
    const int t = threadIdx.x;
    const int b = blockIdx.x / NCHUNK;
    const int sBase = (blockIdx.x - b * NCHUNK) * RPC;

    const int sl = t >> 4;          // staging row 0..15 (and +16)
    const int e0 = (t & 15) << 2;   // elem 0,4,...,60
    const int i0 = (t >> 4) << 2;   // acc tile row base (k index)
    const int j0 = (t & 15) << 2;   // acc tile col base (v index)

    const float* kb = K + (size_t)b * S_ * D_;
    const float* vb = V + (size_t)b * S_ * D_;

    // ---- issue ALL loads up front (16 independent float4s) ----
    const size_t rA  = (size_t)(sBase + sl) * D_ + e0;        // stage A row sl
    const size_t rA2 = rA + 16 * D_;                          // stage A row sl+16
    const size_t rB  = rA + 32 * D_;                          // stage B
    const size_t rB2 = rA + 48 * D_;
    float4 kA  = *(const float4*)(kb + rA);
    float4 vA  = *(const float4*)(vb + rA);
    float4 fA  = *(const float4*)(FK + rA);
    float4 gA  = *(const float4*)(FV + rA);
    float4 kA2 = *(const float4*)(kb + rA2);
    float4 vA2 = *(const float4*)(vb + rA2);
    float4 fA2 = *(const float4*)(FK + rA2);
    float4 gA2 = *(const float4*)(FV + rA2);
    float4 kB  = *(const float4*)(kb + rB);
    float4 vB  = *(const float4*)(vb + rB);
    float4 fB  = *(const float4*)(FK + rB);
    float4 gB  = *(const float4*)(FV + rB);
    float4 kB2 = *(const float4*)(kb + rB2);
    float4 vB2 = *(const float4*)(vb + rB2);
    float4 fB2 = *(const float4*)(FK + rB2);
    float4 gB2 = *(const float4*)(FV + rB2);

    float acc[4][4];
    #pragma unroll
    for (int a = 0; a < 4; ++a)
        #pragma unroll
        for (int c = 0; c < 4; ++c) acc[a][c] = 0.f;

    // ---- stage A: RoPE, stage, compute rows 0..31 ----
    {
        float4 kr, vr, kr2, vr2;
        kr.x  = kA.x*fA.x - kA.y*fA.y;   kr.y  = kA.x*fA.y + kA.y*fA.x;
        kr.z  = kA.z*fA.z - kA.w*fA.w;   kr.w  = kA.z*fA.w + kA.w*fA.z;
        vr.x  = vA.x*gA.x - vA.y*gA.y;   vr.y  = vA.x*gA.y + vA.y*gA.x;
        vr.z  = vA.z*gA.z - vA.w*gA.w;   vr.w  = vA.z*gA.w + vA.w*gA.z;
        kr2.x = kA2.x*fA2.x - kA2.y*fA2.y; kr2.y = kA2.x*fA2.y + kA2.y*fA2.x;
        kr2.z = kA2.z*fA2.z - kA2.w*fA2.w; kr2.w = kA2.z*fA2.w + kA2.w*fA2.z;
        vr2.x = vA2.x*gA2.x - vA2.y*gA2.y; vr2.y = vA2.x*gA2.y + vA2.y*gA2.x;
        vr2.z = vA2.z*gA2.z - vA2.w*gA2.w; vr2.w = vA2.z*gA2.w + vA2.w*gA2.z;
        *(float4*)&kbuf[sl][e0]      = kr;
        *(float4*)&vbuf[sl][e0]      = vr;
        *(float4*)&kbuf[sl + 16][e0] = kr2;
        *(float4*)&vbuf[sl + 16][e0] = vr2;
    }
    __syncthreads();
    #pragma unroll
    for (int r = 0; r < 32; ++r) {
        float4 ka = *(const float4*)&kbuf[r][i0];
        float4 vv = *(const float4*)&vbuf[r][j0];
        acc[0][0] += ka.x*vv.x; acc[0][1] += ka.x*vv.y; acc[0][2] += ka.x*vv.z; acc[0][3] += ka.x*vv.w;
        acc[1][0] += ka.y*vv.x; acc[1][1] += ka.y*vv.y; acc[1][2] += ka.y*vv.z; acc[1][3] += ka.y*vv.w;
        acc[2][0] += ka.z*vv.x; acc[2][1] += ka.z*vv.y; acc[2][2] += ka.z*vv.z; acc[2][3] += ka.z*vv.w;
        acc[3][0] += ka.w*vv.x; acc[3][1] += ka.w*vv.y; acc[3][2] += ka.w*vv.z; acc[3][3] += ka.w*vv.w;
    }
    __syncthreads();

    // ---- stage B: rows 32..63 ----
    {
        float4 kr, vr, kr2, vr2;
        kr.x  = kB.x*fB.x - kB.y*fB.y;   kr.y  = kB.x*fB.y + kB.y*fB.x;
        kr.z  = kB.z*fB.z - kB.w*fB.w;   kr.w  = kB.z*fB.w + kB.w*fB.z;
        vr.x  = vB.x*gB.x - vB.y*gB.y;   vr.y  = vB.x*gB.y + vB.y*gB.x;
        vr.z  = vB.z*gB.z - vB.w*gB.w;   vr.w  = vB.z*gB.w + vB.w*gB.z;
        kr2.x = kB2.x*fB2.x - kB2.y*fB2.y; kr2.y = kB2.x*fB2.y + kB2.y*fB2.x;
        kr2.z = kB2.z*fB2.z - kB2.w*fB2.w; kr2.w = kB2.z*fB2.w + kB2.w*fB2.z;
        vr2.x = vB2.x*gB2.x - vB2.y*gB2.y; vr2.y = vB2.x*gB2.y + vB2.y*gB2.x;
        vr2.z = vB2.z*gB2.z - vB2.w*gB2.w; vr2.w = vB2.z*gB2.w + vB2.w*gB2.z;
        *(float4*)&kbuf[sl][e0]      = kr;
        *(float4*)&vbuf[sl][e0]      = vr;
        *(float4*)&kbuf[sl + 16][e0] = kr2;
        *(float4*)&vbuf[sl + 16][e0] = vr2;
    }
    __syncthreads();
    #pragma unroll
    for (int r = 0; r < 32; ++r) {
        float4 ka = *(const float4*)&kbuf[r][i0];
        float4 vv = *(const float4*)&vbuf[r][j0];
        acc[0][0] += ka.x*vv.x; acc[0][1] += ka.x*vv.y; acc[0][2] += ka.x*vv.z; acc[0][3] += ka.x*vv.w;
        acc[1][0] += ka.y*vv.x; acc[1][1] += ka.y*vv.y; acc[1][2] += ka.y*vv.z; acc[1][3] += ka.y*vv.w;
        acc[2][0] += ka.z*vv.x; acc[2][1] += ka.z*vv.y; acc[2][2] += ka.z*vv.z; acc[2][3] += ka.z*vv.w;
        acc[3][0] += ka.w*vv.x; acc[3][1] += ka.w*vv.y; acc[3][2] += ka.w*vv.z; acc[3][3] += ka.w*vv.w;
    }

    float* p = part + (size_t)blockIdx.x * (D_ * D_);
    #pragma unroll
    for (int a = 0; a < 4; ++a)
        *(float4*)(p + (size_t)(i0 + a) * D_ + j0) =
            make_float4(acc[a][0], acc[a][1], acc[a][2], acc[a][3]);
}

// ---------------------------------------------------------------------------
// Kernel 1.5: reduce 64 partial tiles -> M[b][i*64+j], scale folded.
// Block = (batch b = blk>>6, row i = blk&63). 4 threads per cell, 16
// independent unrolled loads each, LDS 4-way combine. 512 blocks (2/CU).
// ---------------------------------------------------------------------------
__global__ void reduce_partials(const float* __restrict__ part,
                                float* __restrict__ M)
{
    __shared__ float red[4][64];
    const int t   = threadIdx.x;
    const int c   = t & 63;        // column j
    const int q   = t >> 6;        // quarter 0..3
    const int blk = blockIdx.x;
    const int b   = blk >> 6;
    const int i   = blk & 63;

    const float* p = part + ((size_t)b * NCHUNK + q * 16) * (D_ * D_) + i * D_ + c;
    float s0 = 0.f, s1 = 0.f, s2 = 0.f, s3 = 0.f;
    #pragma unroll
    for (int k = 0; k < 4; ++k) {
        s0 += p[(size_t)(4 * k + 0) * (D_ * D_)];
        s1 += p[(size_t)(4 * k + 1) * (D_ * D_)];
        s2 += p[(size_t)(4 * k + 2) * (D_ * D_)];
        s3 += p[(size_t)(4 * k + 3) * (D_ * D_)];
    }
    red[q][c] = (s0 + s1) + (s2 + s3);
    __syncthreads();
    if (t < 64)
        M[(size_t)b * (D_ * D_) + i * D_ + t] =
            0.125f * ((red[0][t] + red[1][t]) + (red[2][t] + red[3][t]));
}

// ---------------------------------------------------------------------------
// Kernel 2: block = (batch, 64-row slab) -> 512 blocks (2/CU). Stage M
// transposed into Mt[64][65] (float4 global loads + 16 scalar LDS scatter),
// RoPE+stage 64 q rows into qbuf[64][68]. Each thread: 4 rows x 4 cols
// register tile: 1024 FMAs vs ~40 LDS ops -> VALU-bound.
// ---------------------------------------------------------------------------
__global__ void rope_q_matmul(
    const float* __restrict__ Q, const float* __restrict__ FQ,
    const float* __restrict__ M, float* __restrict__ OUT)
{
    __shared__ float Mt[64][65];   // Mt[j][i] = scaled M[i][j]
    __shared__ float qbuf[64][68]; // stride 68 -> conflict-free stage + read
    const int t = threadIdx.x;
    const int blk = blockIdx.x;
    const int b = blk >> 6;
    const int rowBase = (blk & 63) * 64;

    // ---- issue global loads: 4 M float4s, 4 q float4s, 4 fq float4s ----
    const float* mb = M + (size_t)b * (D_ * D_);
    float4 m0 = *(const float4*)(mb + (t << 2));
    float4 m1 = *(const float4*)(mb + 1024 + (t << 2));
    float4 m2 = *(const float4*)(mb + 2048 + (t << 2));
    float4 m3 = *(const float4*)(mb + 3072 + (t << 2));

    const int qrow = t >> 2;             // 0..63
    const int e0   = (t & 3) << 4;       // 0,16,32,48
    const float* qb = Q + ((size_t)b * S_ + rowBase + qrow) * D_ + e0;
    const float* fb = FQ + ((size_t)(rowBase + qrow)) * D_ + e0;
    float4 q0 = *(const float4*)(qb + 0),  f0 = *(const float4*)(fb + 0);
    float4 q1 = *(const float4*)(qb + 4),  f1 = *(const float4*)(fb + 4);
    float4 q2 = *(const float4*)(qb + 8),  f2 = *(const float4*)(fb + 8);
    float4 q3 = *(const float4*)(qb + 12), f3 = *(const float4*)(fb + 12);

    // ---- RoPE q and stage ----
    float4 r0, r1, r2, r3;
    r0.x = q0.x*f0.x - q0.y*f0.y;  r0.y = q0.x*f0.y + q0.y*f0.x;
    r0.z = q0.z*f0.z - q0.w*f0.w;  r0.w = q0.z*f0.w + q0.w*f0.z;
    r1.x = q1.x*f1.x - q1.y*f1.y;  r1.y = q1.x*f1.y + q1.y*f1.x;
    r1.z = q1.z*f1.z - q1.w*f1.w;  r1.w = q1.z*f1.w + q1.w*f1.z;
    r2.x = q2.x*f2.x - q2.y*f2.y;  r2.y = q2.x*f2.y + q2.y*f2.x;
    r2.z = q2.z*f2.z - q2.w*f2.w;  r2.w = q2.z*f2.w + q2.w*f2.z;
    r3.x = q3.x*f3.x - q3.y*f3.y;  r3.y = q3.x*f3.y + q3.y*f3.x;
    r3.z = q3.z*f3.z - q3.w*f3.w;  r3.w = q3.z*f3.w + q3.w*f3.z;
    *(float4*)&qbuf[qrow][e0 + 0]  = r0;
    *(float4*)&qbuf[qrow][e0 + 4]  = r1;
    *(float4*)&qbuf[qrow][e0 + 8]  = r2;
    *(float4*)&qbuf[qrow][e0 + 12] = r3;

    // ---- scatter M transposed: cell e = c*1024 + t*4 + d -> Mt[e&63][e>>6]
    {
        const float mv[16] = { m0.x, m0.y, m0.z, m0.w,  m1.x, m1.y, m1.z, m1.w,
                               m2.x, m2.y, m2.z, m2.w,  m3.x, m3.y, m3.z, m3.w };
        const int jBase = (t << 2) & 63;      // j of first element
        const int iIdx0 = (t >> 4);           // i = c*16 + (t>>4)
        #pragma unroll
        for (int c = 0; c < 4; ++c)
            #pragma unroll
            for (int d = 0; d < 4; ++d)
                Mt[jBase + d][c * 16 + iIdx0] = mv[c * 4 + d];
    }
    __syncthreads();

    // ---- 4x4 register tile: rows ty*4+r, cols tx*4+c ----
    const int ty = t >> 4;        // 0..15
    const int tx = t & 15;        // 0..15
    float acc[4][4];
    #pragma unroll
    for (int r = 0; r < 4; ++r)
        #pragma unroll
        for (int c = 0; c < 4; ++c) acc[r][c] = 0.f;

    #pragma unroll
    for (int i = 0; i < 64; i += 4) {
        float4 mtv[4], qv[4];
        #pragma unroll
        for (int c = 0; c < 4; ++c) mtv[c] = *(const float4*)&Mt[tx * 4 + c][i];
        #pragma unroll
        for (int r = 0; r < 4; ++r) qv[r]  = *(const float4*)&qbuf[ty * 4 + r][i];
        #pragma unroll
        for (int r = 0; r < 4; ++r)
            #pragma unroll
            for (int c = 0; c < 4; ++c)
                acc[r][c] += qv[r].x * mtv[c].x + qv[r].y * mtv[c].y +
                             qv[r].z * mtv[c].z + qv[r].w * mtv[c].w;
    }

    float* ob = OUT + ((size_t)b * S_ + rowBase + ty * 4) * D_ + tx * 4;
    #pragma unroll
    for (int r = 0; r < 4; ++r)
        *(float4*)(ob + (size_t)r * D_) =
            make_float4(acc[r][0], acc[r][1], acc[r][2], acc[r][3]);
}

extern "C" void kernel_launch(void* const* d_in, const int* in_sizes, int n_in,
                              void* d_out, int out_size, void* d_ws, size_t ws_size,
                              hipStream_t stream)
{
    const float* Q  = (const float*)d_in[0];
    const float* K  = (const float*)d_in[1];
    const float* V  = (const float*)d_in[2];
    const float* FQ = (const float*)d_in[3];
    const float* FK = (const float*)d_in[4];
    const float* FV = (const float*)d_in[5];
    float* OUT = (float*)d_out;

    float* M    = (float*)d_ws;                          // 128 KB
    float* part = (float*)d_ws + (size_t)B_ * D_ * D_;   // 8.4 MB

    rope_ktv_partials<<<dim3(B_ * NCHUNK), dim3(256), 0, stream>>>(
        K, V, FK, FV, part);

    reduce_partials<<<dim3(B_ * D_), dim3(256), 0, stream>>>(part, M);

    rope_q_matmul<<<dim3(B_ * (S_ / 64)), dim3(256), 0, stream>>>(
        Q, FQ, M, OUT);
}

// Round 5
// 97.524 us; speedup vs baseline: 1.6860x; 1.6860x over previous
//
#include <hip/hip_runtime.h>

#define B_ 8
#define S_ 4096
#define D_ 64
#define NCHUNK 64          // chunks per batch; 64 rows per chunk, 2 stages
#define RPC (S_ / NCHUNK)  // 64 rows per chunk

// ---------------------------------------------------------------------------
// Kernel 1: block = (batch, chunk). Two unrolled 32-row stages; all global
// loads (16 float4/thread) issued before any compute; RoPE in registers;
// 4x4 register-tile outer product from LDS. Writes one 64x64 partial tile.
// __launch_bounds__(256) is load-bearing: without it the compiler assumes
// 1024-thread blocks, caps VGPRs at 64, and spills ~300MB/dispatch (r4 bug).
// ---------------------------------------------------------------------------
__global__ __launch_bounds__(256) void rope_ktv_partials(
    const float* __restrict__ K, const float* __restrict__ V,
    const float* __restrict__ FK, const float* __restrict__ FV,
    float* __restrict__ part)
{
    __shared__ float kbuf[32][64];
    __shared__ float vbuf[32][64];
    const int t = threadIdx.x;
    const int b = blockIdx.x / NCHUNK;
    const int sBase = (blockIdx.x - b * NCHUNK) * RPC;

    const int sl = t >> 4;          // staging row 0..15 (and +16)
    const int e0 = (t & 15) << 2;   // elem 0,4,...,60
    const int i0 = (t >> 4) << 2;   // acc tile row base (k index)
    const int j0 = (t & 15) << 2;   // acc tile col base (v index)

    const float* kb = K + (size_t)b * S_ * D_;
    const float* vb = V + (size_t)b * S_ * D_;

    // ---- issue ALL loads up front (16 independent float4s) ----
    const size_t rA  = (size_t)(sBase + sl) * D_ + e0;
    const size_t rA2 = rA + 16 * D_;
    const size_t rB  = rA + 32 * D_;
    const size_t rB2 = rA + 48 * D_;
    float4 kA  = *(const float4*)(kb + rA);
    float4 vA  = *(const float4*)(vb + rA);
    float4 fA  = *(const float4*)(FK + rA);
    float4 gA  = *(const float4*)(FV + rA);
    float4 kA2 = *(const float4*)(kb + rA2);
    float4 vA2 = *(const float4*)(vb + rA2);
    float4 fA2 = *(const float4*)(FK + rA2);
    float4 gA2 = *(const float4*)(FV + rA2);
    float4 kB  = *(const float4*)(kb + rB);
    float4 vB  = *(const float4*)(vb + rB);
    float4 fB  = *(const float4*)(FK + rB);
    float4 gB  = *(const float4*)(FV + rB);
    float4 kB2 = *(const float4*)(kb + rB2);
    float4 vB2 = *(const float4*)(vb + rB2);
    float4 fB2 = *(const float4*)(FK + rB2);
    float4 gB2 = *(const float4*)(FV + rB2);

    float acc[4][4];
    #pragma unroll
    for (int a = 0; a < 4; ++a)
        #pragma unroll
        for (int c = 0; c < 4; ++c) acc[a][c] = 0.f;

    // ---- stage A: RoPE, stage, compute rows 0..31 ----
    {
        float4 kr, vr, kr2, vr2;
        kr.x  = kA.x*fA.x - kA.y*fA.y;   kr.y  = kA.x*fA.y + kA.y*fA.x;
        kr.z  = kA.z*fA.z - kA.w*fA.w;   kr.w  = kA.z*fA.w + kA.w*fA.z;
        vr.x  = vA.x*gA.x - vA.y*gA.y;   vr.y  = vA.x*gA.y + vA.y*gA.x;
        vr.z  = vA.z*gA.z - vA.w*gA.w;   vr.w  = vA.z*gA.w + vA.w*gA.z;
        kr2.x = kA2.x*fA2.x - kA2.y*fA2.y; kr2.y = kA2.x*fA2.y + kA2.y*fA2.x;
        kr2.z = kA2.z*fA2.z - kA2.w*fA2.w; kr2.w = kA2.z*fA2.w + kA2.w*fA2.z;
        vr2.x = vA2.x*gA2.x - vA2.y*gA2.y; vr2.y = vA2.x*gA2.y + vA2.y*gA2.x;
        vr2.z = vA2.z*gA2.z - vA2.w*gA2.w; vr2.w = vA2.z*gA2.w + vA2.w*gA2.z;
        *(float4*)&kbuf[sl][e0]      = kr;
        *(float4*)&vbuf[sl][e0]      = vr;
        *(float4*)&kbuf[sl + 16][e0] = kr2;
        *(float4*)&vbuf[sl + 16][e0] = vr2;
    }
    __syncthreads();
    #pragma unroll
    for (int r = 0; r < 32; ++r) {
        float4 ka = *(const float4*)&kbuf[r][i0];   // broadcast per 16 lanes
        float4 vv = *(const float4*)&vbuf[r][j0];   // 2-way alias = free
        acc[0][0] += ka.x*vv.x; acc[0][1] += ka.x*vv.y; acc[0][2] += ka.x*vv.z; acc[0][3] += ka.x*vv.w;
        acc[1][0] += ka.y*vv.x; acc[1][1] += ka.y*vv.y; acc[1][2] += ka.y*vv.z; acc[1][3] += ka.y*vv.w;
        acc[2][0] += ka.z*vv.x; acc[2][1] += ka.z*vv.y; acc[2][2] += ka.z*vv.z; acc[2][3] += ka.z*vv.w;
        acc[3][0] += ka.w*vv.x; acc[3][1] += ka.w*vv.y; acc[3][2] += ka.w*vv.z; acc[3][3] += ka.w*vv.w;
    }
    __syncthreads();

    // ---- stage B: rows 32..63 ----
    {
        float4 kr, vr, kr2, vr2;
        kr.x  = kB.x*fB.x - kB.y*fB.y;   kr.y  = kB.x*fB.y + kB.y*fB.x;
        kr.z  = kB.z*fB.z - kB.w*fB.w;   kr.w  = kB.z*fB.w + kB.w*fB.z;
        vr.x  = vB.x*gB.x - vB.y*gB.y;   vr.y  = vB.x*gB.y + vB.y*gB.x;
        vr.z  = vB.z*gB.z - vB.w*gB.w;   vr.w  = vB.z*gB.w + vB.w*gB.z;
        kr2.x = kB2.x*fB2.x - kB2.y*fB2.y; kr2.y = kB2.x*fB2.y + kB2.y*fB2.x;
        kr2.z = kB2.z*fB2.z - kB2.w*fB2.w; kr2.w = kB2.z*fB2.w + kB2.w*fB2.z;
        vr2.x = vB2.x*gB2.x - vB2.y*gB2.y; vr2.y = vB2.x*gB2.y + vB2.y*gB2.x;
        vr2.z = vB2.z*gB2.z - vB2.w*gB2.w; vr2.w = vB2.z*gB2.w + vB2.w*gB2.z;
        *(float4*)&kbuf[sl][e0]      = kr;
        *(float4*)&vbuf[sl][e0]      = vr;
        *(float4*)&kbuf[sl + 16][e0] = kr2;
        *(float4*)&vbuf[sl + 16][e0] = vr2;
    }
    __syncthreads();
    #pragma unroll
    for (int r = 0; r < 32; ++r) {
        float4 ka = *(const float4*)&kbuf[r][i0];
        float4 vv = *(const float4*)&vbuf[r][j0];
        acc[0][0] += ka.x*vv.x; acc[0][1] += ka.x*vv.y; acc[0][2] += ka.x*vv.z; acc[0][3] += ka.x*vv.w;
        acc[1][0] += ka.y*vv.x; acc[1][1] += ka.y*vv.y; acc[1][2] += ka.y*vv.z; acc[1][3] += ka.y*vv.w;
        acc[2][0] += ka.z*vv.x; acc[2][1] += ka.z*vv.y; acc[2][2] += ka.z*vv.z; acc[2][3] += ka.z*vv.w;
        acc[3][0] += ka.w*vv.x; acc[3][1] += ka.w*vv.y; acc[3][2] += ka.w*vv.z; acc[3][3] += ka.w*vv.w;
    }

    float* p = part + (size_t)blockIdx.x * (D_ * D_);
    #pragma unroll
    for (int a = 0; a < 4; ++a)
        *(float4*)(p + (size_t)(i0 + a) * D_ + j0) =
            make_float4(acc[a][0], acc[a][1], acc[a][2], acc[a][3]);
}

// ---------------------------------------------------------------------------
// Kernel 1.5: reduce 64 partial tiles -> M[b][i*64+j], 1/8 scale folded.
// Block = (batch b = blk>>6, row i = blk&63). 4 threads per cell, 16
// independent unrolled coalesced loads each, LDS 4-way combine.
// ---------------------------------------------------------------------------
__global__ __launch_bounds__(256) void reduce_partials(
    const float* __restrict__ part, float* __restrict__ M)
{
    __shared__ float red[4][64];
    const int t   = threadIdx.x;
    const int c   = t & 63;        // column j
    const int q   = t >> 6;        // quarter 0..3
    const int b   = blockIdx.x >> 6;
    const int i   = blockIdx.x & 63;

    const float* p = part + ((size_t)b * NCHUNK + q * 16) * (D_ * D_) + i * D_ + c;
    float s0 = 0.f, s1 = 0.f, s2 = 0.f, s3 = 0.f;
    #pragma unroll
    for (int k = 0; k < 4; ++k) {
        s0 += p[(size_t)(4 * k + 0) * (D_ * D_)];
        s1 += p[(size_t)(4 * k + 1) * (D_ * D_)];
        s2 += p[(size_t)(4 * k + 2) * (D_ * D_)];
        s3 += p[(size_t)(4 * k + 3) * (D_ * D_)];
    }
    red[q][c] = (s0 + s1) + (s2 + s3);
    __syncthreads();
    if (t < 64)
        M[(size_t)b * (D_ * D_) + i * D_ + t] =
            0.125f * ((red[0][t] + red[1][t]) + (red[2][t] + red[3][t]));
}

// ---------------------------------------------------------------------------
// Kernel 2: block = (batch, 64-row slab) -> 512 blocks. M staged via 16
// coalesced scalar loads/thread (M is L2-hot) + conflict-free transposed
// scatter (wave = 64 distinct j, same i -> stride-65 -> 2 lanes/bank).
// q: 4 rows/thread, RoPE in regs. Compute: 4x4 register tile, 1024 FMAs
// vs 64 LDS b128 reads -> VALU-bound.
// ---------------------------------------------------------------------------
__global__ __launch_bounds__(256) void rope_q_matmul(
    const float* __restrict__ Q, const float* __restrict__ FQ,
    const float* __restrict__ M, float* __restrict__ OUT)
{
    __shared__ float Mt[64][65];   // Mt[j][i] = scaled M[i][j]
    __shared__ float qbuf[64][68];
    const int t = threadIdx.x;
    const int b = blockIdx.x >> 6;
    const int rowBase = (blockIdx.x & 63) * 64;

    // ---- issue M loads: 16 coalesced scalars (wave reads 64 consecutive) --
    const int j  = t & 63;         // column of M this thread carries
    const int qq = t >> 6;         // i-quarter 0..3
    const float* mb = M + (size_t)b * (D_ * D_);
    float mreg[16];
    #pragma unroll
    for (int r = 0; r < 16; ++r)
        mreg[r] = mb[(size_t)(qq * 16 + r) * D_ + j];

    // ---- issue q + freq loads: rows sl, sl+16, sl+32, sl+48 ----
    const int sl = t >> 4;
    const int e0 = (t & 15) << 2;
    const float* qb = Q + ((size_t)b * S_ + rowBase + sl) * D_ + e0;
    const float* fb = FQ + ((size_t)(rowBase + sl)) * D_ + e0;
    float4 q0 = *(const float4*)(qb + 0 * 16 * D_), f0 = *(const float4*)(fb + 0 * 16 * D_);
    float4 q1 = *(const float4*)(qb + 1 * 16 * D_), f1 = *(const float4*)(fb + 1 * 16 * D_);
    float4 q2 = *(const float4*)(qb + 2 * 16 * D_), f2 = *(const float4*)(fb + 2 * 16 * D_);
    float4 q3 = *(const float4*)(qb + 3 * 16 * D_), f3 = *(const float4*)(fb + 3 * 16 * D_);

    // ---- RoPE q, stage (2-way max bank alias on writes = free) ----
    float4 r0, r1, r2, r3;
    r0.x = q0.x*f0.x - q0.y*f0.y;  r0.y = q0.x*f0.y + q0.y*f0.x;
    r0.z = q0.z*f0.z - q0.w*f0.w;  r0.w = q0.z*f0.w + q0.w*f0.z;
    r1.x = q1.x*f1.x - q1.y*f1.y;  r1.y = q1.x*f1.y + q1.y*f1.x;
    r1.z = q1.z*f1.z - q1.w*f1.w;  r1.w = q1.z*f1.w + q1.w*f1.z;
    r2.x = q2.x*f2.x - q2.y*f2.y;  r2.y = q2.x*f2.y + q2.y*f2.x;
    r2.z = q2.z*f2.z - q2.w*f2.w;  r2.w = q2.z*f2.w + q2.w*f2.z;
    r3.x = q3.x*f3.x - q3.y*f3.y;  r3.y = q3.x*f3.y + q3.y*f3.x;
    r3.z = q3.z*f3.z - q3.w*f3.w;  r3.w = q3.z*f3.w + q3.w*f3.z;
    *(float4*)&qbuf[sl +  0][e0] = r0;
    *(float4*)&qbuf[sl + 16][e0] = r1;
    *(float4*)&qbuf[sl + 32][e0] = r2;
    *(float4*)&qbuf[sl + 48][e0] = r3;

    // ---- transposed scatter of M: conflict-free (distinct j, same i) ----
    #pragma unroll
    for (int r = 0; r < 16; ++r)
        Mt[j][qq * 16 + r] = mreg[r];
    __syncthreads();

    // ---- 4x4 register tile: rows ty*4+r, cols tx*4+c ----
    const int ty = t >> 4;        // 0..15
    const int tx = t & 15;        // 0..15
    float acc[4][4];
    #pragma unroll
    for (int r = 0; r < 4; ++r)
        #pragma unroll
        for (int c = 0; c < 4; ++c) acc[r][c] = 0.f;

    #pragma unroll
    for (int i = 0; i < 64; i += 4) {
        float4 mtv[4], qv[4];
        #pragma unroll
        for (int c = 0; c < 4; ++c) mtv[c] = *(const float4*)&Mt[tx * 4 + c][i];
        #pragma unroll
        for (int r = 0; r < 4; ++r) qv[r]  = *(const float4*)&qbuf[ty * 4 + r][i];
        #pragma unroll
        for (int r = 0; r < 4; ++r)
            #pragma unroll
            for (int c = 0; c < 4; ++c)
                acc[r][c] += qv[r].x * mtv[c].x + qv[r].y * mtv[c].y +
                             qv[r].z * mtv[c].z + qv[r].w * mtv[c].w;
    }

    float* ob = OUT + ((size_t)b * S_ + rowBase + ty * 4) * D_ + tx * 4;
    #pragma unroll
    for (int r = 0; r < 4; ++r)
        *(float4*)(ob + (size_t)r * D_) =
            make_float4(acc[r][0], acc[r][1], acc[r][2], acc[r][3]);
}

extern "C" void kernel_launch(void* const* d_in, const int* in_sizes, int n_in,
                              void* d_out, int out_size, void* d_ws, size_t ws_size,
                              hipStream_t stream)
{
    const float* Q  = (const float*)d_in[0];
    const float* K  = (const float*)d_in[1];
    const float* V  = (const float*)d_in[2];
    const float* FQ = (const float*)d_in[3];
    const float* FK = (const float*)d_in[4];
    const float* FV = (const float*)d_in[5];
    float* OUT = (float*)d_out;

    float* M    = (float*)d_ws;                          // 128 KB
    float* part = (float*)d_ws + (size_t)B_ * D_ * D_;   // 8.4 MB

    rope_ktv_partials<<<dim3(B_ * NCHUNK), dim3(256), 0, stream>>>(
        K, V, FK, FV, part);

    reduce_partials<<<dim3(B_ * D_), dim3(256), 0, stream>>>(part, M);

    rope_q_matmul<<<dim3(B_ * (S_ / 64)), dim3(256), 0, stream>>>(
        Q, FQ, M, OUT);
}